// Round 1
// baseline (1011.099 us; speedup 1.0000x reference)
//
#include <hip/hip_runtime.h>

typedef __attribute__((ext_vector_type(8))) __bf16 bf16x8;
typedef __attribute__((ext_vector_type(4))) float f32x4;

#define MFMA16(a, b, c) __builtin_amdgcn_mfma_f32_16x16x32_bf16(a, b, c, 0, 0, 0)

#define T_SEQ 512
#define F_IN 32
#define H1 128
#define E2 64
#define ROWS 4          // batch rows per block

__device__ __forceinline__ float bf2f(ushort u) {
    union { uint i; float f; } v; v.i = ((uint)u) << 16; return v.f;
}
__device__ __forceinline__ ushort f2bf(float f) {
    union { float f; uint i; } v; v.f = f;
    uint r = v.i + 0x7fffu + ((v.i >> 16) & 1u);
    return (ushort)(r >> 16);
}
__device__ __forceinline__ float fast_sigmoid(float x) {
    float e = __expf(-x);
    return __builtin_amdgcn_rcpf(1.0f + e);
}
__device__ __forceinline__ float fast_tanh(float x) {
    float e = __expf(-2.0f * x);
    return 2.0f * __builtin_amdgcn_rcpf(1.0f + e) - 1.0f;
}
__device__ __forceinline__ bf16x8 load_w8(const float* p) {
    bf16x8 r;
#pragma unroll
    for (int j = 0; j < 8; ++j) r[j] = (__bf16)p[j];
    return r;
}

// Fused 2-layer LSTM, 128 blocks x 512 threads, 4 batch rows per block.
//
// ROUND THEORY (spill kill): previous rounds' L1 waves held 160 VGPRs of
// weight frags (+acc+temps ~225 peak) vs L2 waves' 96 -> allocator spilled
// ~33 regs/thread (WRITE_SIZE 8.5MB one-time store; per-step scratch reloads
// = the hidden ~2900 cyc/step; VGPR_Count stuck at 128).
// Fix: SYMMETRIC waves. Every wave owns 64 L1 outputs (16 Whh1 + 4 Wih1
// frags = 80 regs) AND 32 L2 outputs (8 Wih2 + 4 Whh2 frags = 48 regs)
// = 128 weight regs/wave, peak live ~180. The shared h1 A-frags are read
// from LDS once per wave and feed BOTH layers' MFMAs. Plus explicit
// amdgpu_waves_per_eu(1,2): we only ever have 2 waves/SIMD resident
// (1 block x 8 waves / 4 SIMDs), so allow the 256-VGPR budget.
__global__ __attribute__((amdgpu_waves_per_eu(1, 2))) __launch_bounds__(512)
void lstm_fused(
    const float* __restrict__ x,      // [512][512][32]
    const float* __restrict__ Wih1,   // [512][32]
    const float* __restrict__ Whh1,   // [512][128]
    const float* __restrict__ bih1,   // [512]
    const float* __restrict__ bhh1,   // [512]
    const float* __restrict__ Wih2,   // [256][128]
    const float* __restrict__ Whh2,   // [256][64]
    const float* __restrict__ bih2,   // [256]
    const float* __restrict__ bhh2,   // [256]
    float* __restrict__ out)          // [512][64] fp32
{
    __shared__ ushort xs [16][72];    // x(t): cols 0..31 hi, 32..63 lo
    __shared__ ushort h1s[16][264];   // h1: cols 0..127 hi, 128..255 lo
    __shared__ ushort h2s[16][136];   // h2: cols 0..63 hi, 64..127 lo
    __shared__ float  g1r[ROWS][516]; // raw L1 gates (valid rows only)
    __shared__ float  g2r[ROWS][260]; // raw L2 gates

    const int tid  = threadIdx.x;
    const int wave = tid >> 6;
    const int lane = tid & 63;
    const int l15  = lane & 15;
    const int quad = lane >> 4;
    const int r0   = blockIdx.x * ROWS;
    const int w64  = wave * 64;       // this wave's L1 gate base
    const int w32  = wave * 32;       // this wave's L2 gate base

    // Weight fragment file, symmetric across all 8 waves (128 VGPRs):
    bf16x8 wh1[4][4];   // Whh1 rows w64+nt*16+l15, k-block kt      (64 regs)
    bf16x8 wx1[4];      // Wih1 rows w64+nt*16+l15                  (16 regs)
    bf16x8 wi2[2][4];   // Wih2 rows w32+mt*16+l15, k-block kt      (32 regs)
    bf16x8 wh2[2][2];   // Whh2 rows w32+mt*16+l15, k-block kt      (16 regs)
    float  b1[4], b2[2];

#pragma unroll
    for (int nt = 0; nt < 4; ++nt) {
        const int n = w64 + nt * 16 + l15;
#pragma unroll
        for (int kt = 0; kt < 4; ++kt)
            wh1[nt][kt] = load_w8(Whh1 + n * H1 + kt * 32 + quad * 8);
        wx1[nt] = load_w8(Wih1 + n * F_IN + quad * 8);
        b1[nt] = bih1[n] + bhh1[n];
    }
#pragma unroll
    for (int mt = 0; mt < 2; ++mt) {
        const int n = w32 + mt * 16 + l15;
#pragma unroll
        for (int kt = 0; kt < 4; ++kt)
            wi2[mt][kt] = load_w8(Wih2 + n * H1 + kt * 32 + quad * 8);
#pragma unroll
        for (int kt = 0; kt < 2; ++kt)
            wh2[mt][kt] = load_w8(Whh2 + n * E2 + kt * 32 + quad * 8);
        b2[mt] = bih2[n] + bhh2[n];
    }

    // zero h states (all 16 rows; rows >= ROWS stay zero forever)
    for (int i = tid; i < 16 * 264; i += 512) ((ushort*)h1s)[i] = 0;
    for (int i = tid; i < 16 * 136; i += 512) ((ushort*)h2s)[i] = 0;
    __syncthreads();

    // per-thread epilogue ownership + fp32 cell state
    const int e1row = tid >> 7, e1u = tid & 127;    // L1: all 512 threads
    const int e2row = tid >> 6, e2u = tid & 63;     // L2: tid < 256
    float c1 = 0.0f, c2 = 0.0f;

    // x prefetch: threads 0..127 own (row = tid>>5, col = tid&31)
    const int xrow = tid >> 5, xcol = tid & 31;
    const float* xptr = x + ((size_t)(r0 + (xrow & 3)) * T_SEQ) * F_IN + xcol;
    float xreg = (tid < 128) ? xptr[0] : 0.0f;

#pragma unroll 1
    for (int tt = 0; tt <= T_SEQ; ++tt) {
        // ---- stage x(tt), prefetch x(tt+1) ----
        if (tt < T_SEQ && tid < 128) {
            const ushort h = f2bf(xreg);
            xs[xrow][xcol]      = h;
            xs[xrow][32 + xcol] = f2bf(xreg - bf2f(h));
            if (tt + 1 < T_SEQ) xreg = xptr[(tt + 1) * F_IN];
        }
        __syncthreads();   // B1: xs(tt), h1(tt-1), h2(tt-2) ready

        // ---- GEMM phase: every wave does its L1 chunk AND its L2 chunk ----
        const bool doL1 = (tt < T_SEQ);
        const bool doL2 = (tt >= 1);
        f32x4 acc1[4], acc2[2];

        if (doL1) {
#pragma unroll
            for (int nt = 0; nt < 4; ++nt)
                acc1[nt] = (f32x4){b1[nt], b1[nt], b1[nt], b1[nt]};
#pragma unroll
            for (int xt = 0; xt < 2; ++xt) {   // x hi, lo (same weight frag)
                const bf16x8 ax = *(const bf16x8*)&xs[l15][xt * 32 + quad * 8];
#pragma unroll
                for (int nt = 0; nt < 4; ++nt)
                    acc1[nt] = MFMA16(ax, wx1[nt], acc1[nt]);
            }
        }
        if (doL2) {
#pragma unroll
            for (int mt = 0; mt < 2; ++mt)
                acc2[mt] = (f32x4){b2[mt], b2[mt], b2[mt], b2[mt]};
        }
        // shared h1(t-1) A-frags feed both layers: kt 0-3 = hi, 4-7 = lo
#pragma unroll
        for (int kt = 0; kt < 8; ++kt) {
            const bf16x8 a = *(const bf16x8*)&h1s[l15][kt * 32 + quad * 8];
            if (doL1) {
#pragma unroll
                for (int nt = 0; nt < 4; ++nt)
                    acc1[nt] = MFMA16(a, wh1[nt][kt & 3], acc1[nt]);
            }
            if (doL2) {
#pragma unroll
                for (int mt = 0; mt < 2; ++mt)
                    acc2[mt] = MFMA16(a, wi2[mt][kt & 3], acc2[mt]);
            }
        }
        if (doL2) {
#pragma unroll
            for (int kt = 0; kt < 4; ++kt) {   // h2 hi (0-1), lo (2-3)
                const bf16x8 a = *(const bf16x8*)&h2s[l15][kt * 32 + quad * 8];
#pragma unroll
                for (int mt = 0; mt < 2; ++mt)
                    acc2[mt] = MFMA16(a, wh2[mt][kt & 1], acc2[mt]);
            }
        }
        if (quad == 0) {   // rows 0..3 are the valid rows
            if (doL1) {
#pragma unroll
                for (int nt = 0; nt < 4; ++nt)
#pragma unroll
                    for (int r = 0; r < ROWS; ++r)
                        g1r[r][w64 + nt * 16 + l15] = acc1[nt][r];
            }
            if (doL2) {
#pragma unroll
                for (int mt = 0; mt < 2; ++mt)
#pragma unroll
                    for (int r = 0; r < ROWS; ++r)
                        g2r[r][w32 + mt * 16 + l15] = acc2[mt][r];
            }
        }
        __syncthreads();   // B2: raw gates ready; h/x MFMA reads done

        // ---- epilogue phase: 1 L1 update/thread; 1 L2 update for tid<256 ----
        if (tt < T_SEQ) {
            const float iv = fast_sigmoid(g1r[e1row][e1u]);
            const float fv = fast_sigmoid(g1r[e1row][128 + e1u]);
            const float gv = fast_tanh   (g1r[e1row][256 + e1u]);
            const float ov = fast_sigmoid(g1r[e1row][384 + e1u]);
            const float cn = fv * c1 + iv * gv;
            c1 = cn;
            const float h = ov * fast_tanh(cn);
            const ushort hi = f2bf(h);
            h1s[e1row][e1u]       = hi;
            h1s[e1row][128 + e1u] = f2bf(h - bf2f(hi));
        }
        if (tid < 256 && tt >= 1) {
            const float iv = fast_sigmoid(g2r[e2row][e2u]);
            const float fv = fast_sigmoid(g2r[e2row][64 + e2u]);
            const float gv = fast_tanh   (g2r[e2row][128 + e2u]);
            const float ov = fast_sigmoid(g2r[e2row][192 + e2u]);
            const float cn = fv * c2 + iv * gv;
            c2 = cn;
            const float h = ov * fast_tanh(cn);
            const ushort hi = f2bf(h);
            h2s[e2row][e2u]      = hi;
            h2s[e2row][64 + e2u] = f2bf(h - bf2f(hi));
            if (tt == T_SEQ)
                out[(size_t)(r0 + e2row) * E2 + e2u] = h;
        }
    }
}

extern "C" void kernel_launch(void* const* d_in, const int* in_sizes, int n_in,
                              void* d_out, int out_size, void* d_ws, size_t ws_size,
                              hipStream_t stream) {
    lstm_fused<<<128, 512, 0, stream>>>(
        (const float*)d_in[0], (const float*)d_in[1], (const float*)d_in[2],
        (const float*)d_in[3], (const float*)d_in[4], (const float*)d_in[5],
        (const float*)d_in[6], (const float*)d_in[7], (const float*)d_in[8],
        (float*)d_out);
}